// Round 4
// baseline (243091.504 us; speedup 1.0000x reference)
//
#include <hip/hip_runtime.h>
#include <hip/hip_bf16.h>

#define M_TOTAL 131072
#define ATT_SCALE 0.17677669529663687f
#define LN_EPS 1e-5f
#define CDIV(a,b) (((a)+(b)-1)/(b))

__global__ void zero1(float* p){ if (threadIdx.x == 0) *p = 0.f; }

// h[r][c] = tok[x[m]][c] + pos[x[m]][c]   (pos indexed by TOKEN ids -- source bug preserved)
__global__ void embed_kernel(const int* __restrict__ x, const float* __restrict__ tok,
                             const float* __restrict__ pos, float* __restrict__ h,
                             int row0, int nrows){
  int total = nrows * 256;
  for (int idx = blockIdx.x * blockDim.x + threadIdx.x; idx < total; idx += gridDim.x * blockDim.x){
    int r = idx >> 8, c = idx & 255;
    int t = x[row0 + r];
    h[idx] = tok[t * 256 + c] + pos[t * 256 + c];
  }
}

// kqv[r][col], col = sel*256 + hh*64 + d ; sel 0=K,1=Q,2=V. One thread per output.
__global__ __launch_bounds__(256)
void qkv_kernel(const float* __restrict__ h, const float* __restrict__ Wk,
                const float* __restrict__ Wq, const float* __restrict__ Wv,
                float* __restrict__ kqv, int nrows, int blk){
  int idx = blockIdx.x * 256 + threadIdx.x;
  if (idx >= nrows * 768) return;
  int col = idx % 768;
  int r   = idx / 768;
  int sel = col >> 8, nn = col & 255, hh = nn >> 6, d = nn & 63;
  const float* W = (sel == 0 ? Wk : sel == 1 ? Wq : Wv)
                   + ((size_t)(blk * 4 + hh) * 256) * 64 + d;   // W[blk][hh][c][d]
  const float* hr = h + (size_t)r * 256;
  float acc = 0.f;
  for (int c = 0; c < 256; ++c) acc = fmaf(hr[c], W[(size_t)c * 64], acc);
  kqv[idx] = acc;
}

// wei[((ls*4+hh)*32+t)*32+s] = SCALE * sum_d K[t][d]*Q[s][d]   (scores = k @ q^T)
__global__ __launch_bounds__(256)
void scores_kernel(const float* __restrict__ kqv, float* __restrict__ wei, int nrows){
  int idx = blockIdx.x * 256 + threadIdx.x;
  if (idx >= nrows * 128) return;
  int s = idx & 31, t = (idx >> 5) & 31, hh = (idx >> 10) & 3, ls = idx >> 12;
  const float* Kp = kqv + (size_t)(ls * 32 + t) * 768 + hh * 64;         // K section
  const float* Qp = kqv + (size_t)(ls * 32 + s) * 768 + 256 + hh * 64;   // Q section
  float acc = 0.f;
  for (int d = 0; d < 64; ++d) acc = fmaf(Kp[d], Qp[d], acc);
  wei[idx] = acc * ATT_SCALE;
}

// causal softmax over s for one (ls,hh,t); s>t set to 0
__global__ __launch_bounds__(256)
void softmax_kernel(float* __restrict__ wei, int nrows){
  int idx = blockIdx.x * 256 + threadIdx.x;   // over (ls,hh,t): nrows*4 items
  if (idx >= nrows * 4) return;
  int t = idx & 31;
  float* w = wei + (size_t)(idx >> 5) * 1024 + (size_t)t * 32;
  float mx = -1e30f;
  for (int s = 0; s <= t; ++s) mx = fmaxf(mx, w[s]);
  float sm = 0.f;
  for (int s = 0; s <= t; ++s){ float e = expf(w[s] - mx); w[s] = e; sm += e; }
  float inv = 1.f / sm;
  for (int s = 0; s < 32; ++s) w[s] = (s <= t) ? w[s] * inv : 0.f;
}

// attn[r][hh*64+d] = sum_s wei[t][s] * V[s][d]
__global__ __launch_bounds__(256)
void pv_kernel(const float* __restrict__ wei, const float* __restrict__ kqv,
               float* __restrict__ attn, int nrows){
  int idx = blockIdx.x * 256 + threadIdx.x;
  if (idx >= nrows * 256) return;
  int d = idx & 63, t = (idx >> 6) & 31, hh = (idx >> 11) & 3, ls = idx >> 13;
  const float* w = wei + (size_t)((ls * 4 + hh) * 32 + t) * 32;
  const float* V = kqv + (size_t)(ls * 32) * 768 + 512 + hh * 64 + d;    // V section
  float acc = 0.f;
  for (int s = 0; s < 32; ++s) acc = fmaf(w[s], V[(size_t)s * 768], acc);
  attn[(size_t)(ls * 32 + t) * 256 + hh * 64 + d] = acc;
}

// C[r][n] = sum_k A[r][k] * B[k][n] + bias[n]  (one thread per output)
template<bool RELU>
__global__ __launch_bounds__(256)
void ngemm(const float* __restrict__ A, const float* __restrict__ B,
           const float* __restrict__ bias, float* __restrict__ C,
           int N, int K, int nrows){
  long idx = (long)blockIdx.x * 256 + threadIdx.x;
  if (idx >= (long)nrows * N) return;
  int n = (int)(idx % N);
  long r = idx / N;
  const float* Ar = A + r * K;
  float acc = bias ? bias[n] : 0.f;
  for (int k = 0; k < K; ++k) acc = fmaf(Ar[k], B[(size_t)k * N + n], acc);
  if (RELU) acc = fmaxf(acc, 0.f);
  C[idx] = acc;
}

// h = LayerNorm(h + po) * g + b   (one thread per row, 3 passes)
__global__ __launch_bounds__(256)
void ln_kernel(float* __restrict__ h, const float* __restrict__ po,
               const float* __restrict__ g, const float* __restrict__ b, int nrows){
  int r = blockIdx.x * 256 + threadIdx.x;
  if (r >= nrows) return;
  float* hr = h + (size_t)r * 256;
  const float* pr = po + (size_t)r * 256;
  float s = 0.f;
  for (int c = 0; c < 256; ++c) s += hr[c] + pr[c];
  float mean = s * (1.f / 256.f);
  float q = 0.f;
  for (int c = 0; c < 256; ++c){ float dv = hr[c] + pr[c] - mean; q += dv * dv; }
  float rstd = rsqrtf(q * (1.f / 256.f) + LN_EPS);
  for (int c = 0; c < 256; ++c) hr[c] = (hr[c] + pr[c] - mean) * rstd * g[c] + b[c];
}

// logits: fp32 store to out + lf scratch for loss. One thread per (r,v).
__global__ __launch_bounds__(256)
void logits_kernel(const float* __restrict__ h, const float* __restrict__ lmW,
                   const float* __restrict__ lmb, float* __restrict__ lf,
                   float* __restrict__ out, int nrows, int row0){
  long idx = (long)blockIdx.x * 256 + threadIdx.x;
  if (idx >= (long)nrows * 65) return;
  int v = (int)(idx % 65);
  int r = (int)(idx / 65);
  const float* hr = h + (size_t)r * 256;
  float acc = lmb[v];
  for (int c = 0; c < 256; ++c) acc = fmaf(hr[c], lmW[c * 65 + v], acc);
  lf[idx] = acc;
  out[(size_t)(row0 + r) * 65 + v] = acc;
}

// per-row NLL -> per-block partial (deterministic tree reduce, no atomics)
__global__ __launch_bounds__(256)
void loss_kernel(const float* __restrict__ lf, const int* __restrict__ y,
                 float* __restrict__ partial, int nrows, int row0){
  __shared__ float red[256];
  int r = blockIdx.x * 256 + threadIdx.x;
  float nll = 0.f;
  if (r < nrows){
    const float* L = lf + (size_t)r * 65;
    float mx = -1e30f;
    for (int v = 0; v < 65; ++v) mx = fmaxf(mx, L[v]);
    float sm = 0.f;
    for (int v = 0; v < 65; ++v) sm += expf(L[v] - mx);
    float lse = mx + logf(sm);
    nll = lse - L[y[row0 + r]];
  }
  red[threadIdx.x] = nll;
  __syncthreads();
  for (int st = 128; st; st >>= 1){
    if (threadIdx.x < st) red[threadIdx.x] += red[threadIdx.x + st];
    __syncthreads();
  }
  if (threadIdx.x == 0) partial[blockIdx.x] = red[0];
}

__global__ __launch_bounds__(256)
void loss_red(const float* __restrict__ partial, int n, float* __restrict__ loss_sum){
  __shared__ float red[256];
  float s = 0.f;
  for (int i = threadIdx.x; i < n; i += 256) s += partial[i];
  red[threadIdx.x] = s;
  __syncthreads();
  for (int st = 128; st; st >>= 1){
    if (threadIdx.x < st) red[threadIdx.x] += red[threadIdx.x + st];
    __syncthreads();
  }
  if (threadIdx.x == 0) *loss_sum += red[0];
}

__global__ void loss_fin(const float* __restrict__ loss_sum, float* __restrict__ out){
  if (threadIdx.x == 0)
    out[(size_t)M_TOTAL * 65] = *loss_sum * (1.f / (float)M_TOTAL);
}

extern "C" void kernel_launch(void* const* d_in, const int* in_sizes, int n_in,
                              void* d_out, int out_size, void* d_ws, size_t ws_size,
                              hipStream_t stream) {
  const int*   x    = (const int*)  d_in[0];
  const int*   y    = (const int*)  d_in[1];
  const float* tok  = (const float*)d_in[2];
  const float* pos  = (const float*)d_in[3];
  const float* Wk   = (const float*)d_in[4];
  const float* Wq   = (const float*)d_in[5];
  const float* Wv   = (const float*)d_in[6];
  const float* Wp   = (const float*)d_in[7];
  const float* bp   = (const float*)d_in[8];
  const float* ln1g = (const float*)d_in[9];
  const float* ln1b = (const float*)d_in[10];
  const float* W1   = (const float*)d_in[11];
  const float* b1   = (const float*)d_in[12];
  const float* W2   = (const float*)d_in[13];
  const float* b2   = (const float*)d_in[14];
  const float* ln2g = (const float*)d_in[15];
  const float* ln2b = (const float*)d_in[16];
  const float* lmW  = (const float*)d_in[17];
  const float* lmb  = (const float*)d_in[18];
  float* out = (float*)d_out;   // reference output dtype is float32

  // ws layout: loss_sum[64] | partial[1024] | per-row fp32 buffers (chunked)
  float* loss_sum = (float*)d_ws;
  float* partial  = loss_sum + 64;
  float* bufs     = partial + 1024;
  const size_t per_row = 2753 * 4;   // h256 + kqv768 + attn256 + po256 + ff1 1024 + wei128 + lf65 floats
  size_t fixed = (size_t)(64 + 1024) * 4;
  size_t avail = ws_size > fixed ? ws_size - fixed : 0;
  long rmax = (long)(avail / per_row) & ~255L;   // multiple of 256 rows (8 seqs)
  if (rmax < 256) rmax = 256;                    // minimum viable chunk (~2.8 MB)
  int R = (int)(rmax < (long)M_TOTAL ? rmax : (long)M_TOTAL);

  float* h    = bufs;
  float* kqv  = h    + (size_t)R * 256;
  float* attn = kqv  + (size_t)R * 768;
  float* po   = attn + (size_t)R * 256;
  float* ff1  = po   + (size_t)R * 256;
  float* wei  = ff1  + (size_t)R * 1024;
  float* lf   = wei  + (size_t)R * 128;

  zero1<<<1, 64, 0, stream>>>(loss_sum);

  for (int row0 = 0; row0 < M_TOTAL; row0 += R){
    int nr = (M_TOTAL - row0) < R ? (M_TOTAL - row0) : R;
    int eg = CDIV(nr * 256, 256); if (eg > 8192) eg = 8192;
    embed_kernel<<<eg, 256, 0, stream>>>(x, tok, pos, h, row0, nr);
    for (int i = 0; i < 8; ++i){
      qkv_kernel<<<nr * 3, 256, 0, stream>>>(h, Wk, Wq, Wv, kqv, nr, i);
      scores_kernel<<<nr / 2, 256, 0, stream>>>(kqv, wei, nr);
      softmax_kernel<<<CDIV(nr * 4, 256), 256, 0, stream>>>(wei, nr);
      pv_kernel<<<nr, 256, 0, stream>>>(wei, kqv, attn, nr);
      ngemm<false><<<nr, 256, 0, stream>>>(attn, Wp + (size_t)i * 65536, bp + i * 256, po, 256, 256, nr);
      ln_kernel<<<CDIV(nr, 256), 256, 0, stream>>>(h, po, ln1g + i * 256, ln1b + i * 256, nr);
      ngemm<true><<<nr * 4, 256, 0, stream>>>(h, W1 + (size_t)i * 262144, b1 + i * 1024, ff1, 1024, 256, nr);
      ngemm<false><<<nr, 256, 0, stream>>>(ff1, W2 + (size_t)i * 262144, b2 + i * 256, po, 256, 1024, nr);
      ln_kernel<<<CDIV(nr, 256), 256, 0, stream>>>(h, po, ln2g + i * 256, ln2b + i * 256, nr);
    }
    logits_kernel<<<CDIV(nr * 65, 256), 256, 0, stream>>>(h, lmW, lmb, lf, out, nr, row0);
    int lb = CDIV(nr, 256);
    loss_kernel<<<lb, 256, 0, stream>>>(lf, y, partial, nr, row0);
    loss_red<<<1, 256, 0, stream>>>(partial, lb, loss_sum);
  }
  loss_fin<<<1, 64, 0, stream>>>(loss_sum, out);
}

// Round 5
// 33225.223 us; speedup vs baseline: 7.3165x; 7.3165x over previous
//
#include <hip/hip_runtime.h>
#include <hip/hip_bf16.h>

#define M_TOTAL 131072
#define ATT_SCALE 0.17677669529663687f
#define LN_EPS 1e-5f
#define CDIV(a,b) (((a)+(b)-1)/(b))

__device__ __forceinline__ float wredsum(float v){
#pragma unroll
  for (int m = 32; m; m >>= 1) v += __shfl_xor(v, m, 64);
  return v;
}

__global__ void zero1(float* p){ if (threadIdx.x == 0) *p = 0.f; }

// h[r][c] = tok[x[m]][c] + pos[x[m]][c]   (pos indexed by TOKEN ids -- source bug preserved)
__global__ void embed_kernel(const int* __restrict__ x, const float* __restrict__ tok,
                             const float* __restrict__ pos, float* __restrict__ h,
                             int row0, int nrows){
  int total = nrows * 256;
  for (int idx = blockIdx.x * blockDim.x + threadIdx.x; idx < total; idx += gridDim.x * blockDim.x){
    int r = idx >> 8, c = idx & 255;
    int t = x[row0 + r];
    h[idx] = tok[t * 256 + c] + pos[t * 256 + c];
  }
}

// ---- shared 64x64 tile GEMM body: C[64][64] tile = A[64][K] @ B[K][64] ----
// As/Bs staging + 4x4 accumulators per thread (256 threads).
#define GEMM_TILE_BODY(A_PTR, LDA, B_PTR, LDB)                                   \
  __shared__ float As[16][68];                                                   \
  __shared__ float Bs[16][64];                                                   \
  const int tx = threadIdx.x & 15, ty = threadIdx.x >> 4;                        \
  const int arow = threadIdx.x >> 2, ac = (threadIdx.x & 3) * 4;                 \
  const int bk = threadIdx.x >> 4, bc = (threadIdx.x & 15) * 4;                  \
  float acc[4][4] = {};                                                          \
  for (int kt = 0; kt < K; kt += 16){                                            \
    float4 av = *(const float4*)((A_PTR) + (size_t)(arow) * (LDA) + kt + ac);    \
    As[ac + 0][arow] = av.x; As[ac + 1][arow] = av.y;                            \
    As[ac + 2][arow] = av.z; As[ac + 3][arow] = av.w;                            \
    *(float4*)&Bs[bk][bc] = *(const float4*)((B_PTR) + (size_t)(kt + bk) * (LDB) + bc); \
    __syncthreads();                                                             \
    _Pragma("unroll")                                                            \
    for (int kk = 0; kk < 16; ++kk){                                             \
      float4 a = *(const float4*)&As[kk][ty * 4];                                \
      float4 b = *(const float4*)&Bs[kk][tx * 4];                                \
      acc[0][0] = fmaf(a.x, b.x, acc[0][0]); acc[0][1] = fmaf(a.x, b.y, acc[0][1]); \
      acc[0][2] = fmaf(a.x, b.z, acc[0][2]); acc[0][3] = fmaf(a.x, b.w, acc[0][3]); \
      acc[1][0] = fmaf(a.y, b.x, acc[1][0]); acc[1][1] = fmaf(a.y, b.y, acc[1][1]); \
      acc[1][2] = fmaf(a.y, b.z, acc[1][2]); acc[1][3] = fmaf(a.y, b.w, acc[1][3]); \
      acc[2][0] = fmaf(a.z, b.x, acc[2][0]); acc[2][1] = fmaf(a.z, b.y, acc[2][1]); \
      acc[2][2] = fmaf(a.z, b.z, acc[2][2]); acc[2][3] = fmaf(a.z, b.w, acc[2][3]); \
      acc[3][0] = fmaf(a.w, b.x, acc[3][0]); acc[3][1] = fmaf(a.w, b.y, acc[3][1]); \
      acc[3][2] = fmaf(a.w, b.z, acc[3][2]); acc[3][3] = fmaf(a.w, b.w, acc[3][3]); \
    }                                                                            \
    __syncthreads();                                                             \
  }

// Standard tiled GEMM: C[r][n] = A[r][:] @ B[:][n] + bias[n], row-major B (ldb=N).
template<bool RELU>
__global__ __launch_bounds__(256)
void gemm_tiled(const float* __restrict__ A, const float* __restrict__ B,
                const float* __restrict__ bias, float* __restrict__ C,
                int N, int K){
  const int rowBase = blockIdx.y * 64, colBase = blockIdx.x * 64;
  GEMM_TILE_BODY(A + (size_t)rowBase * K, K, B + colBase, N)
#pragma unroll
  for (int i = 0; i < 4; ++i){
    int r = rowBase + ty * 4 + i;
#pragma unroll
    for (int j = 0; j < 4; ++j){
      int c = colBase + tx * 4 + j;
      float v = acc[i][j] + (bias ? bias[c] : 0.f);
      if (RELU) v = fmaxf(v, 0.f);
      C[(size_t)r * N + c] = v;
    }
  }
}

// QKV tiled GEMM: each 64-wide output tile is one (sel, head): B = W_sel[blk][hh] as [256][64].
// kqv[r][col], col = sel*256 + hh*64 + d.
__global__ __launch_bounds__(256)
void qkv_tiled(const float* __restrict__ h, const float* __restrict__ Wk,
               const float* __restrict__ Wq, const float* __restrict__ Wv,
               float* __restrict__ kqv, int blk){
  const int sel = blockIdx.x >> 2, hh = blockIdx.x & 3;
  const int rowBase = blockIdx.y * 64, colBase = blockIdx.x * 64;
  const float* W = (sel == 0 ? Wk : sel == 1 ? Wq : Wv) + (size_t)(blk * 4 + hh) * 256 * 64;
  const int K = 256;
  GEMM_TILE_BODY(h + (size_t)rowBase * 256, 256, W, 64)
#pragma unroll
  for (int i = 0; i < 4; ++i){
    int r = rowBase + ty * 4 + i;
#pragma unroll
    for (int j = 0; j < 4; ++j){
      int c = colBase + tx * 4 + j;
      kqv[(size_t)r * 768 + c] = acc[i][j];
    }
  }
}

// wei[((ls*4+hh)*32+t)*32+s] = SCALE * sum_d K[t][d]*Q[s][d]   (scores = k @ q^T)
__global__ __launch_bounds__(256)
void scores_kernel(const float* __restrict__ kqv, float* __restrict__ wei, int nrows){
  int idx = blockIdx.x * 256 + threadIdx.x;
  if (idx >= nrows * 128) return;
  int s = idx & 31, t = (idx >> 5) & 31, hh = (idx >> 10) & 3, ls = idx >> 12;
  const float* Kp = kqv + (size_t)(ls * 32 + t) * 768 + hh * 64;         // K section
  const float* Qp = kqv + (size_t)(ls * 32 + s) * 768 + 256 + hh * 64;   // Q section
  float acc = 0.f;
  for (int d = 0; d < 64; ++d) acc = fmaf(Kp[d], Qp[d], acc);
  wei[idx] = acc * ATT_SCALE;
}

// causal softmax over s for one (ls,hh,t); s>t set to 0
__global__ __launch_bounds__(256)
void softmax_kernel(float* __restrict__ wei, int nrows){
  int idx = blockIdx.x * 256 + threadIdx.x;   // over (ls,hh,t): nrows*4 items
  if (idx >= nrows * 4) return;
  int t = idx & 31;
  float* w = wei + (size_t)(idx >> 5) * 1024 + (size_t)t * 32;
  float mx = -1e30f;
  for (int s = 0; s <= t; ++s) mx = fmaxf(mx, w[s]);
  float sm = 0.f;
  for (int s = 0; s <= t; ++s){ float e = expf(w[s] - mx); w[s] = e; sm += e; }
  float inv = 1.f / sm;
  for (int s = 0; s < 32; ++s) w[s] = (s <= t) ? w[s] * inv : 0.f;
}

// attn[r][hh*64+d] = sum_s wei[t][s] * V[s][d]
__global__ __launch_bounds__(256)
void pv_kernel(const float* __restrict__ wei, const float* __restrict__ kqv,
               float* __restrict__ attn, int nrows){
  int idx = blockIdx.x * 256 + threadIdx.x;
  if (idx >= nrows * 256) return;
  int d = idx & 63, t = (idx >> 6) & 31, hh = (idx >> 11) & 3, ls = idx >> 13;
  const float* w = wei + (size_t)((ls * 4 + hh) * 32 + t) * 32;
  const float* V = kqv + (size_t)(ls * 32) * 768 + 512 + hh * 64 + d;    // V section
  float acc = 0.f;
  for (int s = 0; s < 32; ++s) acc = fmaf(w[s], V[(size_t)s * 768], acc);
  attn[(size_t)(ls * 32 + t) * 256 + hh * 64 + d] = acc;
}

// h = LayerNorm(h + po) * g + b ; one wave per row, 4 rows per block (coalesced)
__global__ __launch_bounds__(256)
void ln_kernel(float* __restrict__ h, const float* __restrict__ po,
               const float* __restrict__ g, const float* __restrict__ b){
  const int w = threadIdx.x >> 6, lane = threadIdx.x & 63;
  const size_t r = (size_t)blockIdx.x * 4 + w;
  float v[4];
  float s = 0.f;
#pragma unroll
  for (int j = 0; j < 4; ++j){
    int c = lane + 64 * j;
    v[j] = h[r * 256 + c] + po[r * 256 + c];
    s += v[j];
  }
  s = wredsum(s);
  float mean = s * (1.f / 256.f);
  float q = 0.f;
#pragma unroll
  for (int j = 0; j < 4; ++j){ float d = v[j] - mean; q += d * d; }
  q = wredsum(q);
  float rstd = rsqrtf(q * (1.f / 256.f) + LN_EPS);
#pragma unroll
  for (int j = 0; j < 4; ++j){
    int c = lane + 64 * j;
    h[r * 256 + c] = (v[j] - mean) * rstd * g[c] + b[c];
  }
}

// logits: fp32 store to out + lf scratch for loss. One thread per (r,v).
__global__ __launch_bounds__(256)
void logits_kernel(const float* __restrict__ h, const float* __restrict__ lmW,
                   const float* __restrict__ lmb, float* __restrict__ lf,
                   float* __restrict__ out, int nrows, int row0){
  long idx = (long)blockIdx.x * 256 + threadIdx.x;
  if (idx >= (long)nrows * 65) return;
  int v = (int)(idx % 65);
  int r = (int)(idx / 65);
  const float* hr = h + (size_t)r * 256;
  float acc = lmb[v];
  for (int c = 0; c < 256; ++c) acc = fmaf(hr[c], lmW[c * 65 + v], acc);
  lf[idx] = acc;
  out[(size_t)(row0 + r) * 65 + v] = acc;
}

// per-row NLL -> per-block partial (deterministic tree reduce, no atomics)
__global__ __launch_bounds__(256)
void loss_kernel(const float* __restrict__ lf, const int* __restrict__ y,
                 float* __restrict__ partial, int nrows, int row0){
  __shared__ float red[256];
  int r = blockIdx.x * 256 + threadIdx.x;
  float nll = 0.f;
  if (r < nrows){
    const float* L = lf + (size_t)r * 65;
    float mx = -1e30f;
    for (int v = 0; v < 65; ++v) mx = fmaxf(mx, L[v]);
    float sm = 0.f;
    for (int v = 0; v < 65; ++v) sm += expf(L[v] - mx);
    float lse = mx + logf(sm);
    nll = lse - L[y[row0 + r]];
  }
  red[threadIdx.x] = nll;
  __syncthreads();
  for (int st = 128; st; st >>= 1){
    if (threadIdx.x < st) red[threadIdx.x] += red[threadIdx.x + st];
    __syncthreads();
  }
  if (threadIdx.x == 0) partial[blockIdx.x] = red[0];
}

__global__ __launch_bounds__(256)
void loss_red(const float* __restrict__ partial, int n, float* __restrict__ loss_sum){
  __shared__ float red[256];
  float s = 0.f;
  for (int i = threadIdx.x; i < n; i += 256) s += partial[i];
  red[threadIdx.x] = s;
  __syncthreads();
  for (int st = 128; st; st >>= 1){
    if (threadIdx.x < st) red[threadIdx.x] += red[threadIdx.x + st];
    __syncthreads();
  }
  if (threadIdx.x == 0) *loss_sum += red[0];
}

__global__ void loss_fin(const float* __restrict__ loss_sum, float* __restrict__ out){
  if (threadIdx.x == 0)
    out[(size_t)M_TOTAL * 65] = *loss_sum * (1.f / (float)M_TOTAL);
}

extern "C" void kernel_launch(void* const* d_in, const int* in_sizes, int n_in,
                              void* d_out, int out_size, void* d_ws, size_t ws_size,
                              hipStream_t stream) {
  const int*   x    = (const int*)  d_in[0];
  const int*   y    = (const int*)  d_in[1];
  const float* tok  = (const float*)d_in[2];
  const float* pos  = (const float*)d_in[3];
  const float* Wk   = (const float*)d_in[4];
  const float* Wq   = (const float*)d_in[5];
  const float* Wv   = (const float*)d_in[6];
  const float* Wp   = (const float*)d_in[7];
  const float* bp   = (const float*)d_in[8];
  const float* ln1g = (const float*)d_in[9];
  const float* ln1b = (const float*)d_in[10];
  const float* W1   = (const float*)d_in[11];
  const float* b1   = (const float*)d_in[12];
  const float* W2   = (const float*)d_in[13];
  const float* b2   = (const float*)d_in[14];
  const float* ln2g = (const float*)d_in[15];
  const float* ln2b = (const float*)d_in[16];
  const float* lmW  = (const float*)d_in[17];
  const float* lmb  = (const float*)d_in[18];
  float* out = (float*)d_out;   // reference output dtype is float32

  // ws layout: loss_sum[64] | partial[1024] | per-row fp32 buffers (chunked)
  float* loss_sum = (float*)d_ws;
  float* partial  = loss_sum + 64;
  float* bufs     = partial + 1024;
  const size_t per_row = 2753 * 4;   // h256 + kqv768 + attn256 + po256 + ff1 1024 + wei128 + lf65 floats
  size_t fixed = (size_t)(64 + 1024) * 4;
  size_t avail = ws_size > fixed ? ws_size - fixed : 0;
  long rmax = (long)(avail / per_row) & ~255L;   // multiple of 256 rows (8 seqs)
  if (rmax < 256) rmax = 256;                    // minimum viable chunk (~2.8 MB)
  int R = (int)(rmax < (long)M_TOTAL ? rmax : (long)M_TOTAL);

  float* h    = bufs;
  float* kqv  = h    + (size_t)R * 256;
  float* attn = kqv  + (size_t)R * 768;
  float* po   = attn + (size_t)R * 256;
  float* ff1  = po   + (size_t)R * 256;
  float* wei  = ff1  + (size_t)R * 1024;
  float* lf   = wei  + (size_t)R * 128;

  zero1<<<1, 64, 0, stream>>>(loss_sum);

  for (int row0 = 0; row0 < M_TOTAL; row0 += R){
    int nr = (M_TOTAL - row0) < R ? (M_TOTAL - row0) : R;
    int eg = CDIV(nr * 256, 256); if (eg > 8192) eg = 8192;
    embed_kernel<<<eg, 256, 0, stream>>>(x, tok, pos, h, row0, nr);
    for (int i = 0; i < 8; ++i){
      dim3 gq(12, nr / 64);
      qkv_tiled<<<gq, 256, 0, stream>>>(h, Wk, Wq, Wv, kqv, i);
      scores_kernel<<<nr / 2, 256, 0, stream>>>(kqv, wei, nr);
      softmax_kernel<<<CDIV(nr * 4, 256), 256, 0, stream>>>(wei, nr);
      pv_kernel<<<nr, 256, 0, stream>>>(wei, kqv, attn, nr);
      dim3 gp(4, nr / 64);
      gemm_tiled<false><<<gp, 256, 0, stream>>>(attn, Wp + (size_t)i * 65536, bp + i * 256, po, 256, 256);
      ln_kernel<<<nr / 4, 256, 0, stream>>>(h, po, ln1g + i * 256, ln1b + i * 256);
      dim3 g1(16, nr / 64);
      gemm_tiled<true><<<g1, 256, 0, stream>>>(h, W1 + (size_t)i * 262144, b1 + i * 1024, ff1, 1024, 256);
      dim3 g2(4, nr / 64);
      gemm_tiled<false><<<g2, 256, 0, stream>>>(ff1, W2 + (size_t)i * 262144, b2 + i * 256, po, 256, 1024);
      ln_kernel<<<nr / 4, 256, 0, stream>>>(h, po, ln2g + i * 256, ln2b + i * 256);
    }
    logits_kernel<<<CDIV(nr * 65, 256), 256, 0, stream>>>(h, lmW, lmb, lf, out, nr, row0);
    int lb = CDIV(nr, 256);
    loss_kernel<<<lb, 256, 0, stream>>>(lf, y, partial, nr, row0);
    loss_red<<<1, 256, 0, stream>>>(partial, lb, loss_sum);
  }
  loss_fin<<<1, 64, 0, stream>>>(loss_sum, out);
}

// Round 6
// 16898.528 us; speedup vs baseline: 14.3854x; 1.9662x over previous
//
#include <hip/hip_runtime.h>
#include <hip/hip_bf16.h>

#define M_TOTAL 131072
#define ATT_SCALE 0.17677669529663687f
#define LN_EPS 1e-5f
#define CDIV(a,b) (((a)+(b)-1)/(b))

using bf16x8 = __attribute__((ext_vector_type(8))) short;
using f32x4  = __attribute__((ext_vector_type(4))) float;

__device__ __forceinline__ float wredsum(float v){
#pragma unroll
  for (int m = 32; m; m >>= 1) v += __shfl_xor(v, m, 64);
  return v;
}

// fp32 -> bf16 (round-to-nearest-even) as raw bits
__device__ __forceinline__ unsigned short f2b(float x){
  union { float f; unsigned u; } v; v.f = x;
  unsigned r = v.u + 0x7FFFu + ((v.u >> 16) & 1u);
  return (unsigned short)(r >> 16);
}

__global__ void zero1(float* p){ if (threadIdx.x == 0) *p = 0.f; }

// ---- one-time weight conversion: fp32 [K][N] -> bf16 transposed [N][K] ----
// WrT[i][n][k], n = sel*256 + hh*64 + d  (QKV fused, kqv col order)
__global__ void convert_qkv(const float* __restrict__ Wk, const float* __restrict__ Wq,
                            const float* __restrict__ Wv, unsigned short* __restrict__ WrT){
  int idx = blockIdx.x * 256 + threadIdx.x;   // [i][n][k], k fastest (coalesced writes)
  if (idx >= 8 * 768 * 256) return;
  int k = idx & 255;
  int n = (idx >> 8) % 768;
  int i = idx / (768 * 256);
  int sel = n >> 8, nn = n & 255, hh = nn >> 6, d = nn & 63;
  const float* W = sel == 0 ? Wk : sel == 1 ? Wq : Wv;
  WrT[idx] = f2b(W[((size_t)(i * 4 + hh) * 256 + k) * 64 + d]);
}

__global__ void convert_t(const float* __restrict__ in, unsigned short* __restrict__ outp,
                          int N, int K, int total){
  int idx = blockIdx.x * 256 + threadIdx.x;   // [i][n][k], k fastest
  if (idx >= total) return;
  int k = idx % K;
  int n = (idx / K) % N;
  int i = idx / (K * N);
  outp[idx] = f2b(in[((size_t)i * K + k) * N + n]);
}

// ---- MFMA bf16 GEMM: C[r][n] = A[r][:] @ B[:][n] + bias[n] ----
// A fp32 row-major [M][K] (converted to bf16 in staging); BT bf16 transposed [N][K].
// 128x128 tile, BK=32, 256 threads = 4 waves in 2x2, each wave 64x64 = 4x4 MFMA frags.
template<bool RELU>
__global__ __launch_bounds__(256)
void gemm_mfma(const float* __restrict__ A, const unsigned short* __restrict__ BT,
               const float* __restrict__ bias, float* __restrict__ C,
               int N, int K){
  __shared__ unsigned short As[128][40];   // [m][k], pad 32->40 breaks 8-way conflicts
  __shared__ unsigned short Bs[128][40];   // [n][k]
  const int tid = threadIdx.x;
  const int rowBase = blockIdx.y * 128, colBase = blockIdx.x * 128;
  const int w = tid >> 6, lane = tid & 63;
  const int wm = w >> 1, wn = w & 1;
  const int lm = lane & 15, lk = lane >> 4;      // frag row/col = lm ; k-group = lk*8
  const int sr = tid >> 1, sk = (tid & 1) * 16;  // staging: row 0..127, k-half 0/16

  f32x4 acc[4][4];
#pragma unroll
  for (int m = 0; m < 4; ++m)
#pragma unroll
    for (int n = 0; n < 4; ++n) acc[m][n] = (f32x4){0.f, 0.f, 0.f, 0.f};

  for (int kt = 0; kt < K; kt += 32){
    // stage A (fp32 -> bf16): 16 elements/thread
    const float* Ap = A + (size_t)(rowBase + sr) * K + kt + sk;
    float4 f0 = ((const float4*)Ap)[0];
    float4 f1 = ((const float4*)Ap)[1];
    float4 f2 = ((const float4*)Ap)[2];
    float4 f3 = ((const float4*)Ap)[3];
    union { unsigned short s[8]; uint4 v; } u0, u1;
    u0.s[0]=f2b(f0.x); u0.s[1]=f2b(f0.y); u0.s[2]=f2b(f0.z); u0.s[3]=f2b(f0.w);
    u0.s[4]=f2b(f1.x); u0.s[5]=f2b(f1.y); u0.s[6]=f2b(f1.z); u0.s[7]=f2b(f1.w);
    u1.s[0]=f2b(f2.x); u1.s[1]=f2b(f2.y); u1.s[2]=f2b(f2.z); u1.s[3]=f2b(f2.w);
    u1.s[4]=f2b(f3.x); u1.s[5]=f2b(f3.y); u1.s[6]=f2b(f3.z); u1.s[7]=f2b(f3.w);
    *(uint4*)&As[sr][sk]     = u0.v;
    *(uint4*)&As[sr][sk + 8] = u1.v;
    // stage B (bf16 copy): 16 elements/thread
    const uint4* Bp = (const uint4*)(BT + (size_t)(colBase + sr) * K + kt + sk);
    *(uint4*)&Bs[sr][sk]     = Bp[0];
    *(uint4*)&Bs[sr][sk + 8] = Bp[1];
    __syncthreads();

    bf16x8 a[4], b[4];
#pragma unroll
    for (int m = 0; m < 4; ++m)
      a[m] = *(const bf16x8*)&As[wm * 64 + m * 16 + lm][lk * 8];
#pragma unroll
    for (int n = 0; n < 4; ++n)
      b[n] = *(const bf16x8*)&Bs[wn * 64 + n * 16 + lm][lk * 8];
#pragma unroll
    for (int m = 0; m < 4; ++m)
#pragma unroll
      for (int n = 0; n < 4; ++n)
        acc[m][n] = __builtin_amdgcn_mfma_f32_16x16x32_bf16(a[m], b[n], acc[m][n], 0, 0, 0);
    __syncthreads();
  }

#pragma unroll
  for (int m = 0; m < 4; ++m){
#pragma unroll
    for (int n = 0; n < 4; ++n){
      int c = colBase + wn * 64 + n * 16 + lm;
      float bv = bias ? bias[c] : 0.f;
#pragma unroll
      for (int i = 0; i < 4; ++i){
        int r = rowBase + wm * 64 + m * 16 + lk * 4 + i;
        float v = acc[m][n][i] + bv;
        if (RELU) v = fmaxf(v, 0.f);
        C[(size_t)r * N + c] = v;
      }
    }
  }
}

// h[r][c] = tok[x[m]][c] + pos[x[m]][c]   (pos indexed by TOKEN ids -- source bug preserved)
__global__ void embed_kernel(const int* __restrict__ x, const float* __restrict__ tok,
                             const float* __restrict__ pos, float* __restrict__ h,
                             int row0, int nrows){
  int total = nrows * 256;
  for (int idx = blockIdx.x * blockDim.x + threadIdx.x; idx < total; idx += gridDim.x * blockDim.x){
    int r = idx >> 8, c = idx & 255;
    int t = x[row0 + r];
    h[idx] = tok[t * 256 + c] + pos[t * 256 + c];
  }
}

// wei[((ls*4+hh)*32+t)*32+s] = SCALE * sum_d K[t][d]*Q[s][d]   (scores = k @ q^T)
__global__ __launch_bounds__(256)
void scores_kernel(const float* __restrict__ kqv, float* __restrict__ wei, int nrows){
  int idx = blockIdx.x * 256 + threadIdx.x;
  if (idx >= nrows * 128) return;
  int s = idx & 31, t = (idx >> 5) & 31, hh = (idx >> 10) & 3, ls = idx >> 12;
  const float* Kp = kqv + (size_t)(ls * 32 + t) * 768 + hh * 64;         // K section
  const float* Qp = kqv + (size_t)(ls * 32 + s) * 768 + 256 + hh * 64;   // Q section
  float acc = 0.f;
  for (int d = 0; d < 64; ++d) acc = fmaf(Kp[d], Qp[d], acc);
  wei[idx] = acc * ATT_SCALE;
}

// causal softmax over s for one (ls,hh,t); s>t set to 0
__global__ __launch_bounds__(256)
void softmax_kernel(float* __restrict__ wei, int nrows){
  int idx = blockIdx.x * 256 + threadIdx.x;   // over (ls,hh,t): nrows*4 items
  if (idx >= nrows * 4) return;
  int t = idx & 31;
  float* w = wei + (size_t)(idx >> 5) * 1024 + (size_t)t * 32;
  float mx = -1e30f;
  for (int s = 0; s <= t; ++s) mx = fmaxf(mx, w[s]);
  float sm = 0.f;
  for (int s = 0; s <= t; ++s){ float e = expf(w[s] - mx); w[s] = e; sm += e; }
  float inv = 1.f / sm;
  for (int s = 0; s < 32; ++s) w[s] = (s <= t) ? w[s] * inv : 0.f;
}

// attn[r][hh*64+d] = sum_s wei[t][s] * V[s][d]
__global__ __launch_bounds__(256)
void pv_kernel(const float* __restrict__ wei, const float* __restrict__ kqv,
               float* __restrict__ attn, int nrows){
  int idx = blockIdx.x * 256 + threadIdx.x;
  if (idx >= nrows * 256) return;
  int d = idx & 63, t = (idx >> 6) & 31, hh = (idx >> 11) & 3, ls = idx >> 13;
  const float* w = wei + (size_t)((ls * 4 + hh) * 32 + t) * 32;
  const float* V = kqv + (size_t)(ls * 32) * 768 + 512 + hh * 64 + d;    // V section
  float acc = 0.f;
  for (int s = 0; s < 32; ++s) acc = fmaf(w[s], V[(size_t)s * 768], acc);
  attn[(size_t)(ls * 32 + t) * 256 + hh * 64 + d] = acc;
}

// h = LayerNorm(h + po) * g + b ; one wave per row, 4 rows per block (coalesced)
__global__ __launch_bounds__(256)
void ln_kernel(float* __restrict__ h, const float* __restrict__ po,
               const float* __restrict__ g, const float* __restrict__ b){
  const int w = threadIdx.x >> 6, lane = threadIdx.x & 63;
  const size_t r = (size_t)blockIdx.x * 4 + w;
  float v[4];
  float s = 0.f;
#pragma unroll
  for (int j = 0; j < 4; ++j){
    int c = lane + 64 * j;
    v[j] = h[r * 256 + c] + po[r * 256 + c];
    s += v[j];
  }
  s = wredsum(s);
  float mean = s * (1.f / 256.f);
  float q = 0.f;
#pragma unroll
  for (int j = 0; j < 4; ++j){ float d = v[j] - mean; q += d * d; }
  q = wredsum(q);
  float rstd = rsqrtf(q * (1.f / 256.f) + LN_EPS);
#pragma unroll
  for (int j = 0; j < 4; ++j){
    int c = lane + 64 * j;
    h[r * 256 + c] = (v[j] - mean) * rstd * g[c] + b[c];
  }
}

// logits: fp32 store to out + lf scratch for loss. One thread per (r,v).
__global__ __launch_bounds__(256)
void logits_kernel(const float* __restrict__ h, const float* __restrict__ lmW,
                   const float* __restrict__ lmb, float* __restrict__ lf,
                   float* __restrict__ out, int nrows, int row0){
  long idx = (long)blockIdx.x * 256 + threadIdx.x;
  if (idx >= (long)nrows * 65) return;
  int v = (int)(idx % 65);
  int r = (int)(idx / 65);
  const float* hr = h + (size_t)r * 256;
  float acc = lmb[v];
  for (int c = 0; c < 256; ++c) acc = fmaf(hr[c], lmW[c * 65 + v], acc);
  lf[idx] = acc;
  out[(size_t)(row0 + r) * 65 + v] = acc;
}

// per-row NLL -> per-block partial (deterministic tree reduce, no atomics)
__global__ __launch_bounds__(256)
void loss_kernel(const float* __restrict__ lf, const int* __restrict__ y,
                 float* __restrict__ partial, int nrows, int row0){
  __shared__ float red[256];
  int r = blockIdx.x * 256 + threadIdx.x;
  float nll = 0.f;
  if (r < nrows){
    const float* L = lf + (size_t)r * 65;
    float mx = -1e30f;
    for (int v = 0; v < 65; ++v) mx = fmaxf(mx, L[v]);
    float sm = 0.f;
    for (int v = 0; v < 65; ++v) sm += expf(L[v] - mx);
    float lse = mx + logf(sm);
    nll = lse - L[y[row0 + r]];
  }
  red[threadIdx.x] = nll;
  __syncthreads();
  for (int st = 128; st; st >>= 1){
    if (threadIdx.x < st) red[threadIdx.x] += red[threadIdx.x + st];
    __syncthreads();
  }
  if (threadIdx.x == 0) partial[blockIdx.x] = red[0];
}

__global__ __launch_bounds__(256)
void loss_red(const float* __restrict__ partial, int n, float* __restrict__ loss_sum){
  __shared__ float red[256];
  float s = 0.f;
  for (int i = threadIdx.x; i < n; i += 256) s += partial[i];
  red[threadIdx.x] = s;
  __syncthreads();
  for (int st = 128; st; st >>= 1){
    if (threadIdx.x < st) red[threadIdx.x] += red[threadIdx.x + st];
    __syncthreads();
  }
  if (threadIdx.x == 0) *loss_sum += red[0];
}

__global__ void loss_fin(const float* __restrict__ loss_sum, float* __restrict__ out){
  if (threadIdx.x == 0)
    out[(size_t)M_TOTAL * 65] = *loss_sum * (1.f / (float)M_TOTAL);
}

extern "C" void kernel_launch(void* const* d_in, const int* in_sizes, int n_in,
                              void* d_out, int out_size, void* d_ws, size_t ws_size,
                              hipStream_t stream) {
  const int*   x    = (const int*)  d_in[0];
  const int*   y    = (const int*)  d_in[1];
  const float* tok  = (const float*)d_in[2];
  const float* pos  = (const float*)d_in[3];
  const float* Wk   = (const float*)d_in[4];
  const float* Wq   = (const float*)d_in[5];
  const float* Wv   = (const float*)d_in[6];
  const float* Wp   = (const float*)d_in[7];
  const float* bp   = (const float*)d_in[8];
  const float* ln1g = (const float*)d_in[9];
  const float* ln1b = (const float*)d_in[10];
  const float* W1   = (const float*)d_in[11];
  const float* b1   = (const float*)d_in[12];
  const float* W2   = (const float*)d_in[13];
  const float* b2   = (const float*)d_in[14];
  const float* ln2g = (const float*)d_in[15];
  const float* ln2b = (const float*)d_in[16];
  const float* lmW  = (const float*)d_in[17];
  const float* lmb  = (const float*)d_in[18];
  float* out = (float*)d_out;   // reference output dtype is float32

  // ws layout: loss_sum[64] | partial[1024] | bf16 weights (transposed) | per-row fp32 buffers
  float* loss_sum = (float*)d_ws;
  float* partial  = loss_sum + 64;
  unsigned short* WrT = (unsigned short*)(partial + 1024);       // [8][768][256]
  unsigned short* WpT = WrT + (size_t)8 * 768 * 256;             // [8][256][256]
  unsigned short* W1T = WpT + (size_t)8 * 256 * 256;             // [8][1024][256]
  unsigned short* W2T = W1T + (size_t)8 * 1024 * 256;            // [8][256][1024]
  float* bufs = (float*)(W2T + (size_t)8 * 256 * 1024);
  size_t fixed = (size_t)(64 + 1024) * 4 +
                 ((size_t)8 * 768 * 256 + 8 * 256 * 256 + 8 * 1024 * 256 + 8 * 256 * 1024) * 2;
  const size_t per_row = 2753 * 4;   // h256 + kqv768 + attn256 + po256 + ff1 1024 + wei128 + lf65
  size_t avail = ws_size > fixed ? ws_size - fixed : 0;
  long rmax = (long)(avail / per_row) & ~255L;   // multiple of 256 rows
  if (rmax < 256) rmax = 256;
  int R = (int)(rmax < (long)M_TOTAL ? rmax : (long)M_TOTAL);

  float* h    = bufs;
  float* kqv  = h    + (size_t)R * 256;
  float* attn = kqv  + (size_t)R * 768;
  float* po   = attn + (size_t)R * 256;
  float* ff1  = po   + (size_t)R * 256;
  float* wei  = ff1  + (size_t)R * 1024;
  float* lf   = wei  + (size_t)R * 128;

  zero1<<<1, 64, 0, stream>>>(loss_sum);
  convert_qkv<<<CDIV(8 * 768 * 256, 256), 256, 0, stream>>>(Wk, Wq, Wv, WrT);
  convert_t<<<CDIV(8 * 256 * 256, 256), 256, 0, stream>>>(Wp, WpT, 256, 256, 8 * 256 * 256);
  convert_t<<<CDIV(8 * 1024 * 256, 256), 256, 0, stream>>>(W1, W1T, 1024, 256, 8 * 1024 * 256);
  convert_t<<<CDIV(8 * 256 * 1024, 256), 256, 0, stream>>>(W2, W2T, 256, 1024, 8 * 256 * 1024);

  for (int row0 = 0; row0 < M_TOTAL; row0 += R){
    int nr = (M_TOTAL - row0) < R ? (M_TOTAL - row0) : R;
    int eg = CDIV(nr * 256, 256); if (eg > 8192) eg = 8192;
    embed_kernel<<<eg, 256, 0, stream>>>(x, tok, pos, h, row0, nr);
    for (int i = 0; i < 8; ++i){
      gemm_mfma<false><<<dim3(6, nr / 128), 256, 0, stream>>>(
          h, WrT + (size_t)i * 768 * 256, nullptr, kqv, 768, 256);
      scores_kernel<<<nr / 2, 256, 0, stream>>>(kqv, wei, nr);
      softmax_kernel<<<CDIV(nr * 4, 256), 256, 0, stream>>>(wei, nr);
      pv_kernel<<<nr, 256, 0, stream>>>(wei, kqv, attn, nr);
      gemm_mfma<false><<<dim3(2, nr / 128), 256, 0, stream>>>(
          attn, WpT + (size_t)i * 256 * 256, bp + i * 256, po, 256, 256);
      ln_kernel<<<nr / 4, 256, 0, stream>>>(h, po, ln1g + i * 256, ln1b + i * 256);
      gemm_mfma<true><<<dim3(8, nr / 128), 256, 0, stream>>>(
          h, W1T + (size_t)i * 1024 * 256, b1 + i * 1024, ff1, 1024, 256);
      gemm_mfma<false><<<dim3(2, nr / 128), 256, 0, stream>>>(
          ff1, W2T + (size_t)i * 256 * 1024, b2 + i * 256, po, 256, 1024);
      ln_kernel<<<nr / 4, 256, 0, stream>>>(h, po, ln2g + i * 256, ln2b + i * 256);
    }
    logits_kernel<<<CDIV(nr * 65, 256), 256, 0, stream>>>(h, lmW, lmb, lf, out, nr, row0);
    int lb = CDIV(nr, 256);
    loss_kernel<<<lb, 256, 0, stream>>>(lf, y, partial, nr, row0);
    loss_red<<<1, 256, 0, stream>>>(partial, lb, loss_sum);
  }
  loss_fin<<<1, 64, 0, stream>>>(loss_sum, out);
}

// Round 7
// 10718.344 us; speedup vs baseline: 22.6799x; 1.5766x over previous
//
#include <hip/hip_runtime.h>
#include <hip/hip_bf16.h>

#define M_TOTAL 131072
#define ATT_SCALE 0.17677669529663687f
#define LN_EPS 1e-5f
#define CDIV(a,b) (((a)+(b)-1)/(b))

using bf16x8 = __attribute__((ext_vector_type(8))) short;
using f32x4  = __attribute__((ext_vector_type(4))) float;

__device__ __forceinline__ float wredsum(float v){
#pragma unroll
  for (int m = 32; m; m >>= 1) v += __shfl_xor(v, m, 64);
  return v;
}

// fp32 -> bf16 (round-to-nearest-even) as raw bits
__device__ __forceinline__ unsigned short f2b(float x){
  union { float f; unsigned u; } v; v.f = x;
  unsigned r = v.u + 0x7FFFu + ((v.u >> 16) & 1u);
  return (unsigned short)(r >> 16);
}

__global__ void zero1(float* p){ if (threadIdx.x == 0) *p = 0.f; }

// ---- one-time weight conversion: fp32 [K][N] -> bf16 transposed [N][K] ----
// WrT[i][n][k], n = sel*256 + hh*64 + d  (QKV fused, kqv col order)
__global__ void convert_qkv(const float* __restrict__ Wk, const float* __restrict__ Wq,
                            const float* __restrict__ Wv, unsigned short* __restrict__ WrT){
  int idx = blockIdx.x * 256 + threadIdx.x;   // [i][n][k], k fastest (coalesced writes)
  if (idx >= 8 * 768 * 256) return;
  int k = idx & 255;
  int n = (idx >> 8) % 768;
  int i = idx / (768 * 256);
  int sel = n >> 8, nn = n & 255, hh = nn >> 6, d = nn & 63;
  const float* W = sel == 0 ? Wk : sel == 1 ? Wq : Wv;
  WrT[idx] = f2b(W[((size_t)(i * 4 + hh) * 256 + k) * 64 + d]);
}

__global__ void convert_t(const float* __restrict__ in, unsigned short* __restrict__ outp,
                          int N, int K, int total){
  int idx = blockIdx.x * 256 + threadIdx.x;   // [i][n][k], k fastest
  if (idx >= total) return;
  int k = idx % K;
  int n = (idx / K) % N;
  int i = idx / (K * N);
  outp[idx] = f2b(in[((size_t)i * K + k) * N + n]);
}

// ---- MFMA bf16 GEMM: C[r][n] = A[r][:] @ B[:][n] + bias[n] ----
// A fp32 row-major [M][K] (converted to bf16 in staging); BT bf16 transposed [N][K].
// 128x128 tile, BK=32, 256 threads = 4 waves in 2x2, each wave 64x64 = 4x4 MFMA frags.
template<bool RELU>
__global__ __launch_bounds__(256)
void gemm_mfma(const float* __restrict__ A, const unsigned short* __restrict__ BT,
               const float* __restrict__ bias, float* __restrict__ C,
               int N, int K){
  __shared__ unsigned short As[128][40];   // [m][k], pad 32->40 breaks 8-way conflicts
  __shared__ unsigned short Bs[128][40];   // [n][k]
  const int tid = threadIdx.x;
  const int rowBase = blockIdx.y * 128, colBase = blockIdx.x * 128;
  const int w = tid >> 6, lane = tid & 63;
  const int wm = w >> 1, wn = w & 1;
  const int lm = lane & 15, lk = lane >> 4;      // frag row/col = lm ; k-group = lk*8
  const int sr = tid >> 1, sk = (tid & 1) * 16;  // staging: row 0..127, k-half 0/16

  f32x4 acc[4][4];
#pragma unroll
  for (int m = 0; m < 4; ++m)
#pragma unroll
    for (int n = 0; n < 4; ++n) acc[m][n] = (f32x4){0.f, 0.f, 0.f, 0.f};

  for (int kt = 0; kt < K; kt += 32){
    // stage A (fp32 -> bf16): 16 elements/thread
    const float* Ap = A + (size_t)(rowBase + sr) * K + kt + sk;
    float4 f0 = ((const float4*)Ap)[0];
    float4 f1 = ((const float4*)Ap)[1];
    float4 f2 = ((const float4*)Ap)[2];
    float4 f3 = ((const float4*)Ap)[3];
    union { unsigned short s[8]; uint4 v; } u0, u1;
    u0.s[0]=f2b(f0.x); u0.s[1]=f2b(f0.y); u0.s[2]=f2b(f0.z); u0.s[3]=f2b(f0.w);
    u0.s[4]=f2b(f1.x); u0.s[5]=f2b(f1.y); u0.s[6]=f2b(f1.z); u0.s[7]=f2b(f1.w);
    u1.s[0]=f2b(f2.x); u1.s[1]=f2b(f2.y); u1.s[2]=f2b(f2.z); u1.s[3]=f2b(f2.w);
    u1.s[4]=f2b(f3.x); u1.s[5]=f2b(f3.y); u1.s[6]=f2b(f3.z); u1.s[7]=f2b(f3.w);
    *(uint4*)&As[sr][sk]     = u0.v;
    *(uint4*)&As[sr][sk + 8] = u1.v;
    // stage B (bf16 copy): 16 elements/thread
    const uint4* Bp = (const uint4*)(BT + (size_t)(colBase + sr) * K + kt + sk);
    *(uint4*)&Bs[sr][sk]     = Bp[0];
    *(uint4*)&Bs[sr][sk + 8] = Bp[1];
    __syncthreads();

    bf16x8 a[4], b[4];
#pragma unroll
    for (int m = 0; m < 4; ++m)
      a[m] = *(const bf16x8*)&As[wm * 64 + m * 16 + lm][lk * 8];
#pragma unroll
    for (int n = 0; n < 4; ++n)
      b[n] = *(const bf16x8*)&Bs[wn * 64 + n * 16 + lm][lk * 8];
#pragma unroll
    for (int m = 0; m < 4; ++m)
#pragma unroll
      for (int n = 0; n < 4; ++n)
        acc[m][n] = __builtin_amdgcn_mfma_f32_16x16x32_bf16(a[m], b[n], acc[m][n], 0, 0, 0);
    __syncthreads();
  }

#pragma unroll
  for (int m = 0; m < 4; ++m){
#pragma unroll
    for (int n = 0; n < 4; ++n){
      int c = colBase + wn * 64 + n * 16 + lm;
      float bv = bias ? bias[c] : 0.f;
#pragma unroll
      for (int i = 0; i < 4; ++i){
        int r = rowBase + wm * 64 + m * 16 + lk * 4 + i;
        float v = acc[m][n][i] + bv;
        if (RELU) v = fmaxf(v, 0.f);
        C[(size_t)r * N + c] = v;
      }
    }
  }
}

// h[r][c] = tok[x[m]][c] + pos[x[m]][c]   (pos indexed by TOKEN ids -- source bug preserved)
__global__ void embed_kernel(const int* __restrict__ x, const float* __restrict__ tok,
                             const float* __restrict__ pos, float* __restrict__ h,
                             int row0, int nrows){
  int total = nrows * 256;
  for (int idx = blockIdx.x * blockDim.x + threadIdx.x; idx < total; idx += gridDim.x * blockDim.x){
    int r = idx >> 8, c = idx & 255;
    int t = x[row0 + r];
    h[idx] = tok[t * 256 + c] + pos[t * 256 + c];
  }
}

// ---- fused attention: one block per (seq, head), 128 threads ----
// scores = K @ Q^T * SCALE (source semantics), causal softmax, out = wei @ V.
// FMA order matches the previous separate kernels exactly (d asc, s asc).
__global__ __launch_bounds__(128)
void attn_fused(const float* __restrict__ kqv, float* __restrict__ attn){
  __shared__ float Kf[32][68];   // [t][d], pad 68: scores read is broadcast over t
  __shared__ float Qt[64][33];   // [d][s] transposed: bank = (d*33+s)&31, s distinct
  __shared__ float Vf[32][68];   // [s][d], b128 reads 2-way (free)
  __shared__ float Ws[32][33];
  const int ls = blockIdx.x, hh = blockIdx.y;
  const int tid = threadIdx.x;

  for (int idx = tid; idx < 2048; idx += 128){
    int t = idx >> 6, d = idx & 63;
    size_t base = (size_t)(ls * 32 + t) * 768 + hh * 64 + d;
    Kf[t][d] = kqv[base];
    Qt[d][t] = kqv[base + 256];
    Vf[t][d] = kqv[base + 512];
  }
  __syncthreads();

  for (int idx = tid; idx < 1024; idx += 128){
    int s = idx & 31, t = idx >> 5;
    if (s <= t){
      float acc = 0.f;
#pragma unroll 16
      for (int d = 0; d < 64; ++d) acc = fmaf(Kf[t][d], Qt[d][s], acc);
      Ws[t][s] = acc * ATT_SCALE;
    }
  }
  __syncthreads();

  if (tid < 32){
    int t = tid;
    float mx = -1e30f;
    for (int s = 0; s <= t; ++s) mx = fmaxf(mx, Ws[t][s]);
    float sm = 0.f;
    for (int s = 0; s <= t; ++s){ float e = expf(Ws[t][s] - mx); Ws[t][s] = e; sm += e; }
    float inv = 1.f / sm;
    for (int s = 0; s <= t; ++s) Ws[t][s] *= inv;
    for (int s = t + 1; s < 32; ++s) Ws[t][s] = 0.f;
  }
  __syncthreads();

  for (int o = tid; o < 512; o += 128){
    int t = o >> 4, d4 = o & 15;
    float4 a4 = {0.f, 0.f, 0.f, 0.f};
#pragma unroll
    for (int s = 0; s < 32; ++s){
      float w = Ws[t][s];
      float4 v = *(const float4*)&Vf[s][d4 * 4];
      a4.x = fmaf(w, v.x, a4.x); a4.y = fmaf(w, v.y, a4.y);
      a4.z = fmaf(w, v.z, a4.z); a4.w = fmaf(w, v.w, a4.w);
    }
    *(float4*)(attn + (size_t)(ls * 32 + t) * 256 + hh * 64 + d4 * 4) = a4;
  }
}

// h = LayerNorm(h + po) * g + b ; one wave per row, 4 rows per block (coalesced)
__global__ __launch_bounds__(256)
void ln_kernel(float* __restrict__ h, const float* __restrict__ po,
               const float* __restrict__ g, const float* __restrict__ b){
  const int w = threadIdx.x >> 6, lane = threadIdx.x & 63;
  const size_t r = (size_t)blockIdx.x * 4 + w;
  float v[4];
  float s = 0.f;
#pragma unroll
  for (int j = 0; j < 4; ++j){
    int c = lane + 64 * j;
    v[j] = h[r * 256 + c] + po[r * 256 + c];
    s += v[j];
  }
  s = wredsum(s);
  float mean = s * (1.f / 256.f);
  float q = 0.f;
#pragma unroll
  for (int j = 0; j < 4; ++j){ float d = v[j] - mean; q += d * d; }
  q = wredsum(q);
  float rstd = rsqrtf(q * (1.f / 256.f) + LN_EPS);
#pragma unroll
  for (int j = 0; j < 4; ++j){
    int c = lane + 64 * j;
    h[r * 256 + c] = (v[j] - mean) * rstd * g[c] + b[c];
  }
}

// logits: fp32 store to out + lf scratch for loss. One thread per (r,v).
__global__ __launch_bounds__(256)
void logits_kernel(const float* __restrict__ h, const float* __restrict__ lmW,
                   const float* __restrict__ lmb, float* __restrict__ lf,
                   float* __restrict__ out, int nrows, int row0){
  long idx = (long)blockIdx.x * 256 + threadIdx.x;
  if (idx >= (long)nrows * 65) return;
  int v = (int)(idx % 65);
  int r = (int)(idx / 65);
  const float* hr = h + (size_t)r * 256;
  float acc = lmb[v];
  for (int c = 0; c < 256; ++c) acc = fmaf(hr[c], lmW[c * 65 + v], acc);
  lf[idx] = acc;
  out[(size_t)(row0 + r) * 65 + v] = acc;
}

// per-row NLL -> per-block partial (deterministic tree reduce, no atomics)
__global__ __launch_bounds__(256)
void loss_kernel(const float* __restrict__ lf, const int* __restrict__ y,
                 float* __restrict__ partial, int nrows, int row0){
  __shared__ float red[256];
  int r = blockIdx.x * 256 + threadIdx.x;
  float nll = 0.f;
  if (r < nrows){
    const float* L = lf + (size_t)r * 65;
    float mx = -1e30f;
    for (int v = 0; v < 65; ++v) mx = fmaxf(mx, L[v]);
    float sm = 0.f;
    for (int v = 0; v < 65; ++v) sm += expf(L[v] - mx);
    float lse = mx + logf(sm);
    nll = lse - L[y[row0 + r]];
  }
  red[threadIdx.x] = nll;
  __syncthreads();
  for (int st = 128; st; st >>= 1){
    if (threadIdx.x < st) red[threadIdx.x] += red[threadIdx.x + st];
    __syncthreads();
  }
  if (threadIdx.x == 0) partial[blockIdx.x] = red[0];
}

__global__ __launch_bounds__(256)
void loss_red(const float* __restrict__ partial, int n, float* __restrict__ loss_sum){
  __shared__ float red[256];
  float s = 0.f;
  for (int i = threadIdx.x; i < n; i += 256) s += partial[i];
  red[threadIdx.x] = s;
  __syncthreads();
  for (int st = 128; st; st >>= 1){
    if (threadIdx.x < st) red[threadIdx.x] += red[threadIdx.x + st];
    __syncthreads();
  }
  if (threadIdx.x == 0) *loss_sum += red[0];
}

__global__ void loss_fin(const float* __restrict__ loss_sum, float* __restrict__ out){
  if (threadIdx.x == 0)
    out[(size_t)M_TOTAL * 65] = *loss_sum * (1.f / (float)M_TOTAL);
}

extern "C" void kernel_launch(void* const* d_in, const int* in_sizes, int n_in,
                              void* d_out, int out_size, void* d_ws, size_t ws_size,
                              hipStream_t stream) {
  const int*   x    = (const int*)  d_in[0];
  const int*   y    = (const int*)  d_in[1];
  const float* tok  = (const float*)d_in[2];
  const float* pos  = (const float*)d_in[3];
  const float* Wk   = (const float*)d_in[4];
  const float* Wq   = (const float*)d_in[5];
  const float* Wv   = (const float*)d_in[6];
  const float* Wp   = (const float*)d_in[7];
  const float* bp   = (const float*)d_in[8];
  const float* ln1g = (const float*)d_in[9];
  const float* ln1b = (const float*)d_in[10];
  const float* W1   = (const float*)d_in[11];
  const float* b1   = (const float*)d_in[12];
  const float* W2   = (const float*)d_in[13];
  const float* b2   = (const float*)d_in[14];
  const float* ln2g = (const float*)d_in[15];
  const float* ln2b = (const float*)d_in[16];
  const float* lmW  = (const float*)d_in[17];
  const float* lmb  = (const float*)d_in[18];
  float* out = (float*)d_out;   // reference output dtype is float32

  // ws layout: loss_sum[64] | partial[1024] | bf16 weights (transposed) | per-row fp32 buffers
  float* loss_sum = (float*)d_ws;
  float* partial  = loss_sum + 64;
  unsigned short* WrT = (unsigned short*)(partial + 1024);       // [8][768][256]
  unsigned short* WpT = WrT + (size_t)8 * 768 * 256;             // [8][256][256]
  unsigned short* W1T = WpT + (size_t)8 * 256 * 256;             // [8][1024][256]
  unsigned short* W2T = W1T + (size_t)8 * 1024 * 256;            // [8][256][1024]
  float* bufs = (float*)(W2T + (size_t)8 * 256 * 1024);
  size_t fixed = (size_t)(64 + 1024) * 4 +
                 ((size_t)8 * 768 * 256 + 8 * 256 * 256 + 8 * 1024 * 256 + 8 * 256 * 1024) * 2;
  const size_t per_row = 2625 * 4;   // h256 + kqv768 + attn256 + po256 + ff1 1024 + lf65
  size_t avail = ws_size > fixed ? ws_size - fixed : 0;
  long rmax = (long)(avail / per_row) & ~255L;   // multiple of 256 rows
  if (rmax < 256) rmax = 256;
  int R = (int)(rmax < (long)M_TOTAL ? rmax : (long)M_TOTAL);

  float* h    = bufs;
  float* kqv  = h    + (size_t)R * 256;
  float* attn = kqv  + (size_t)R * 768;
  float* po   = attn + (size_t)R * 256;
  float* ff1  = po   + (size_t)R * 256;
  float* lf   = ff1  + (size_t)R * 1024;

  zero1<<<1, 64, 0, stream>>>(loss_sum);
  convert_qkv<<<CDIV(8 * 768 * 256, 256), 256, 0, stream>>>(Wk, Wq, Wv, WrT);
  convert_t<<<CDIV(8 * 256 * 256, 256), 256, 0, stream>>>(Wp, WpT, 256, 256, 8 * 256 * 256);
  convert_t<<<CDIV(8 * 1024 * 256, 256), 256, 0, stream>>>(W1, W1T, 1024, 256, 8 * 1024 * 256);
  convert_t<<<CDIV(8 * 256 * 1024, 256), 256, 0, stream>>>(W2, W2T, 256, 1024, 8 * 256 * 1024);

  for (int row0 = 0; row0 < M_TOTAL; row0 += R){
    int nr = (M_TOTAL - row0) < R ? (M_TOTAL - row0) : R;
    int eg = CDIV(nr * 256, 256); if (eg > 8192) eg = 8192;
    embed_kernel<<<eg, 256, 0, stream>>>(x, tok, pos, h, row0, nr);
    for (int i = 0; i < 8; ++i){
      gemm_mfma<false><<<dim3(6, nr / 128), 256, 0, stream>>>(
          h, WrT + (size_t)i * 768 * 256, nullptr, kqv, 768, 256);
      attn_fused<<<dim3(nr / 32, 4), 128, 0, stream>>>(kqv, attn);
      gemm_mfma<false><<<dim3(2, nr / 128), 256, 0, stream>>>(
          attn, WpT + (size_t)i * 256 * 256, bp + i * 256, po, 256, 256);
      ln_kernel<<<nr / 4, 256, 0, stream>>>(h, po, ln1g + i * 256, ln1b + i * 256);
      gemm_mfma<true><<<dim3(8, nr / 128), 256, 0, stream>>>(
          h, W1T + (size_t)i * 1024 * 256, b1 + i * 1024, ff1, 1024, 256);
      gemm_mfma<false><<<dim3(2, nr / 128), 256, 0, stream>>>(
          ff1, W2T + (size_t)i * 256 * 1024, b2 + i * 256, po, 256, 1024);
      ln_kernel<<<nr / 4, 256, 0, stream>>>(h, po, ln2g + i * 256, ln2b + i * 256);
    }
    logits_kernel<<<CDIV(nr * 65, 256), 256, 0, stream>>>(h, lmW, lmb, lf, out, nr, row0);
    int lb = CDIV(nr, 256);
    loss_kernel<<<lb, 256, 0, stream>>>(lf, y, partial, nr, row0);
    loss_red<<<1, 256, 0, stream>>>(partial, lb, loss_sum);
  }
  loss_fin<<<1, 64, 0, stream>>>(loss_sum, out);
}

// Round 8
// 8435.353 us; speedup vs baseline: 28.8182x; 1.2706x over previous
//
#include <hip/hip_runtime.h>
#include <hip/hip_bf16.h>

#define M_TOTAL 131072
#define ATT_SCALE 0.17677669529663687f
#define LN_EPS 1e-5f
#define CDIV(a,b) (((a)+(b)-1)/(b))

using bf16x8 = __attribute__((ext_vector_type(8))) short;
using f32x4  = __attribute__((ext_vector_type(4))) float;

__device__ __forceinline__ float wredsum(float v){
#pragma unroll
  for (int m = 32; m; m >>= 1) v += __shfl_xor(v, m, 64);
  return v;
}

// fp32 -> bf16 (round-to-nearest-even) as raw bits
__device__ __forceinline__ unsigned short f2b(float x){
  union { float f; unsigned u; } v; v.f = x;
  unsigned r = v.u + 0x7FFFu + ((v.u >> 16) & 1u);
  return (unsigned short)(r >> 16);
}

__global__ void zero1(float* p){ if (threadIdx.x == 0) *p = 0.f; }

// ---- one-time weight conversion: fp32 [K][N] -> bf16 transposed [N][K] ----
__global__ void convert_qkv(const float* __restrict__ Wk, const float* __restrict__ Wq,
                            const float* __restrict__ Wv, unsigned short* __restrict__ WrT){
  int idx = blockIdx.x * 256 + threadIdx.x;   // [i][n][k], k fastest (coalesced writes)
  if (idx >= 8 * 768 * 256) return;
  int k = idx & 255;
  int n = (idx >> 8) % 768;
  int i = idx / (768 * 256);
  int sel = n >> 8, nn = n & 255, hh = nn >> 6, d = nn & 63;
  const float* W = sel == 0 ? Wk : sel == 1 ? Wq : Wv;
  WrT[idx] = f2b(W[((size_t)(i * 4 + hh) * 256 + k) * 64 + d]);
}

__global__ void convert_t(const float* __restrict__ in, unsigned short* __restrict__ outp,
                          int N, int K, int total){
  int idx = blockIdx.x * 256 + threadIdx.x;   // [i][n][k], k fastest
  if (idx >= total) return;
  int k = idx % K;
  int n = (idx / K) % N;
  int i = idx / (K * N);
  outp[idx] = f2b(in[((size_t)i * K + k) * N + n]);
}

// ---- MFMA bf16 GEMM: C[r][n] = A[r][:] @ B[:][n] + bias[n] ----
// A bf16 [M][K]; BT bf16 transposed [N][K]. 128x128 tile, BK=64,
// 256 threads = 4 waves (2x2), each wave 64x64 = 4x4 MFMA frags.
// K-slices consumed ascending -> accumulation order identical to BK=32 version.
template<bool RELU, bool BF16OUT>
__global__ __launch_bounds__(256)
void gemm_bf(const unsigned short* __restrict__ A, const unsigned short* __restrict__ BT,
             const float* __restrict__ bias, float* __restrict__ Cf,
             unsigned short* __restrict__ Cb, int N, int K){
  __shared__ unsigned short As[128][72];   // row stride 144B = 20 banks -> 2-way (free)
  __shared__ unsigned short Bs[128][72];
  const int tid = threadIdx.x;
  const int rowBase = blockIdx.y * 128, colBase = blockIdx.x * 128;
  const int w = tid >> 6, lane = tid & 63;
  const int wm = w >> 1, wn = w & 1;
  const int lm = lane & 15, lk = lane >> 4;
  const int srow = tid >> 3, scol = (tid & 7) * 8;   // 8 lanes x 16B = 128B coalesced

  f32x4 acc[4][4];
#pragma unroll
  for (int m = 0; m < 4; ++m)
#pragma unroll
    for (int n = 0; n < 4; ++n) acc[m][n] = (f32x4){0.f, 0.f, 0.f, 0.f};

  for (int kt = 0; kt < K; kt += 64){
#pragma unroll
    for (int q = 0; q < 4; ++q){
      int r = srow + 32 * q;
      *(uint4*)&As[r][scol] = *(const uint4*)(A  + (size_t)(rowBase + r) * K + kt + scol);
      *(uint4*)&Bs[r][scol] = *(const uint4*)(BT + (size_t)(colBase + r) * K + kt + scol);
    }
    __syncthreads();
#pragma unroll
    for (int half = 0; half < 2; ++half){
      bf16x8 a[4], b[4];
#pragma unroll
      for (int m = 0; m < 4; ++m)
        a[m] = *(const bf16x8*)&As[wm * 64 + m * 16 + lm][half * 32 + lk * 8];
#pragma unroll
      for (int n = 0; n < 4; ++n)
        b[n] = *(const bf16x8*)&Bs[wn * 64 + n * 16 + lm][half * 32 + lk * 8];
#pragma unroll
      for (int m = 0; m < 4; ++m)
#pragma unroll
        for (int n = 0; n < 4; ++n)
          acc[m][n] = __builtin_amdgcn_mfma_f32_16x16x32_bf16(a[m], b[n], acc[m][n], 0, 0, 0);
    }
    __syncthreads();
  }

#pragma unroll
  for (int m = 0; m < 4; ++m){
#pragma unroll
    for (int n = 0; n < 4; ++n){
      int c = colBase + wn * 64 + n * 16 + lm;
      float bv = bias ? bias[c] : 0.f;
#pragma unroll
      for (int i = 0; i < 4; ++i){
        int r = rowBase + wm * 64 + m * 16 + lk * 4 + i;
        float v = acc[m][n][i] + bv;
        if (RELU) v = fmaxf(v, 0.f);
        if (BF16OUT) Cb[(size_t)r * N + c] = f2b(v);
        else         Cf[(size_t)r * N + c] = v;
      }
    }
  }
}

// h[r][c] = tok[x[m]][c] + pos[x[m]][c] (pos indexed by TOKEN ids -- source bug preserved)
// also emits bf16 copy for GEMM A-input (same RNE rounding GEMM used before)
__global__ void embed_kernel(const int* __restrict__ x, const float* __restrict__ tok,
                             const float* __restrict__ pos, float* __restrict__ h,
                             unsigned short* __restrict__ h_bf, int row0, int nrows){
  int total = nrows * 256;
  for (int idx = blockIdx.x * blockDim.x + threadIdx.x; idx < total; idx += gridDim.x * blockDim.x){
    int r = idx >> 8, c = idx & 255;
    int t = x[row0 + r];
    float v = tok[t * 256 + c] + pos[t * 256 + c];
    h[idx] = v;
    h_bf[idx] = f2b(v);
  }
}

// ---- fused attention: one block per (seq, head), 128 threads ----
// scores = K @ Q^T * SCALE (source semantics), causal softmax, out = wei @ V.
// Output written directly as bf16 (only consumer is the proj GEMM).
__global__ __launch_bounds__(128)
void attn_fused(const float* __restrict__ kqv, unsigned short* __restrict__ attn){
  __shared__ float Kf[32][68];
  __shared__ float Qt[64][33];
  __shared__ float Vf[32][68];
  __shared__ float Ws[32][33];
  const int ls = blockIdx.x, hh = blockIdx.y;
  const int tid = threadIdx.x;

  for (int idx = tid; idx < 2048; idx += 128){
    int t = idx >> 6, d = idx & 63;
    size_t base = (size_t)(ls * 32 + t) * 768 + hh * 64 + d;
    Kf[t][d] = kqv[base];
    Qt[d][t] = kqv[base + 256];
    Vf[t][d] = kqv[base + 512];
  }
  __syncthreads();

  for (int idx = tid; idx < 1024; idx += 128){
    int s = idx & 31, t = idx >> 5;
    if (s <= t){
      float acc = 0.f;
#pragma unroll 16
      for (int d = 0; d < 64; ++d) acc = fmaf(Kf[t][d], Qt[d][s], acc);
      Ws[t][s] = acc * ATT_SCALE;
    }
  }
  __syncthreads();

  if (tid < 32){
    int t = tid;
    float mx = -1e30f;
    for (int s = 0; s <= t; ++s) mx = fmaxf(mx, Ws[t][s]);
    float sm = 0.f;
    for (int s = 0; s <= t; ++s){ float e = expf(Ws[t][s] - mx); Ws[t][s] = e; sm += e; }
    float inv = 1.f / sm;
    for (int s = 0; s <= t; ++s) Ws[t][s] *= inv;
    for (int s = t + 1; s < 32; ++s) Ws[t][s] = 0.f;
  }
  __syncthreads();

  for (int o = tid; o < 512; o += 128){
    int t = o >> 4, d4 = o & 15;
    float4 a4 = {0.f, 0.f, 0.f, 0.f};
#pragma unroll
    for (int s = 0; s < 32; ++s){
      float w = Ws[t][s];
      float4 v = *(const float4*)&Vf[s][d4 * 4];
      a4.x = fmaf(w, v.x, a4.x); a4.y = fmaf(w, v.y, a4.y);
      a4.z = fmaf(w, v.z, a4.z); a4.w = fmaf(w, v.w, a4.w);
    }
    ushort4 o4;
    o4.x = f2b(a4.x); o4.y = f2b(a4.y); o4.z = f2b(a4.z); o4.w = f2b(a4.w);
    *(ushort4*)(attn + (size_t)(ls * 32 + t) * 256 + hh * 64 + d4 * 4) = o4;
  }
}

// h = LayerNorm(h + po) * g + b ; one wave per row, 4 rows per block; emits bf16 copy
__global__ __launch_bounds__(256)
void ln_kernel(float* __restrict__ h, const float* __restrict__ po,
               const float* __restrict__ g, const float* __restrict__ b,
               unsigned short* __restrict__ h_bf){
  const int w = threadIdx.x >> 6, lane = threadIdx.x & 63;
  const size_t r = (size_t)blockIdx.x * 4 + w;
  float v[4];
  float s = 0.f;
#pragma unroll
  for (int j = 0; j < 4; ++j){
    int c = lane + 64 * j;
    v[j] = h[r * 256 + c] + po[r * 256 + c];
    s += v[j];
  }
  s = wredsum(s);
  float mean = s * (1.f / 256.f);
  float q = 0.f;
#pragma unroll
  for (int j = 0; j < 4; ++j){ float d = v[j] - mean; q += d * d; }
  q = wredsum(q);
  float rstd = rsqrtf(q * (1.f / 256.f) + LN_EPS);
#pragma unroll
  for (int j = 0; j < 4; ++j){
    int c = lane + 64 * j;
    float nv = (v[j] - mean) * rstd * g[c] + b[c];
    h[r * 256 + c] = nv;
    h_bf[r * 256 + c] = f2b(nv);
  }
}

// logits: fp32 store to out + lf scratch for loss. One thread per (r,v).
__global__ __launch_bounds__(256)
void logits_kernel(const float* __restrict__ h, const float* __restrict__ lmW,
                   const float* __restrict__ lmb, float* __restrict__ lf,
                   float* __restrict__ out, int nrows, int row0){
  long idx = (long)blockIdx.x * 256 + threadIdx.x;
  if (idx >= (long)nrows * 65) return;
  int v = (int)(idx % 65);
  int r = (int)(idx / 65);
  const float* hr = h + (size_t)r * 256;
  float acc = lmb[v];
  for (int c = 0; c < 256; ++c) acc = fmaf(hr[c], lmW[c * 65 + v], acc);
  lf[idx] = acc;
  out[(size_t)(row0 + r) * 65 + v] = acc;
}

// per-row NLL -> per-block partial (deterministic tree reduce, no atomics)
__global__ __launch_bounds__(256)
void loss_kernel(const float* __restrict__ lf, const int* __restrict__ y,
                 float* __restrict__ partial, int nrows, int row0){
  __shared__ float red[256];
  int r = blockIdx.x * 256 + threadIdx.x;
  float nll = 0.f;
  if (r < nrows){
    const float* L = lf + (size_t)r * 65;
    float mx = -1e30f;
    for (int v = 0; v < 65; ++v) mx = fmaxf(mx, L[v]);
    float sm = 0.f;
    for (int v = 0; v < 65; ++v) sm += expf(L[v] - mx);
    float lse = mx + logf(sm);
    nll = lse - L[y[row0 + r]];
  }
  red[threadIdx.x] = nll;
  __syncthreads();
  for (int st = 128; st; st >>= 1){
    if (threadIdx.x < st) red[threadIdx.x] += red[threadIdx.x + st];
    __syncthreads();
  }
  if (threadIdx.x == 0) partial[blockIdx.x] = red[0];
}

__global__ __launch_bounds__(256)
void loss_red(const float* __restrict__ partial, int n, float* __restrict__ loss_sum){
  __shared__ float red[256];
  float s = 0.f;
  for (int i = threadIdx.x; i < n; i += 256) s += partial[i];
  red[threadIdx.x] = s;
  __syncthreads();
  for (int st = 128; st; st >>= 1){
    if (threadIdx.x < st) red[threadIdx.x] += red[threadIdx.x + st];
    __syncthreads();
  }
  if (threadIdx.x == 0) *loss_sum += red[0];
}

__global__ void loss_fin(const float* __restrict__ loss_sum, float* __restrict__ out){
  if (threadIdx.x == 0)
    out[(size_t)M_TOTAL * 65] = *loss_sum * (1.f / (float)M_TOTAL);
}

extern "C" void kernel_launch(void* const* d_in, const int* in_sizes, int n_in,
                              void* d_out, int out_size, void* d_ws, size_t ws_size,
                              hipStream_t stream) {
  const int*   x    = (const int*)  d_in[0];
  const int*   y    = (const int*)  d_in[1];
  const float* tok  = (const float*)d_in[2];
  const float* pos  = (const float*)d_in[3];
  const float* Wk   = (const float*)d_in[4];
  const float* Wq   = (const float*)d_in[5];
  const float* Wv   = (const float*)d_in[6];
  const float* Wp   = (const float*)d_in[7];
  const float* bp   = (const float*)d_in[8];
  const float* ln1g = (const float*)d_in[9];
  const float* ln1b = (const float*)d_in[10];
  const float* W1   = (const float*)d_in[11];
  const float* b1   = (const float*)d_in[12];
  const float* W2   = (const float*)d_in[13];
  const float* b2   = (const float*)d_in[14];
  const float* ln2g = (const float*)d_in[15];
  const float* ln2b = (const float*)d_in[16];
  const float* lmW  = (const float*)d_in[17];
  const float* lmb  = (const float*)d_in[18];
  float* out = (float*)d_out;

  // ws layout: loss_sum[64] | partial[1024] | bf16 weights (transposed) | per-row buffers
  float* loss_sum = (float*)d_ws;
  float* partial  = loss_sum + 64;
  unsigned short* WrT = (unsigned short*)(partial + 1024);       // [8][768][256]
  unsigned short* WpT = WrT + (size_t)8 * 768 * 256;             // [8][256][256]
  unsigned short* W1T = WpT + (size_t)8 * 256 * 256;             // [8][1024][256]
  unsigned short* W2T = W1T + (size_t)8 * 1024 * 256;            // [8][256][1024]
  float* bufs = (float*)(W2T + (size_t)8 * 256 * 1024);
  size_t fixed = (size_t)(64 + 1024) * 4 +
                 ((size_t)8 * 768 * 256 + 8 * 256 * 256 + 8 * 1024 * 256 + 8 * 256 * 1024) * 2;
  // per-row: h256 kqv768 po256 (f32) + h_bf256 attn_bf256 ff1_bf1024 (bf16) + lf65 (f32)
  const size_t per_row = (size_t)(256 + 768 + 256 + 65) * 4 + (size_t)(256 + 256 + 1024) * 2;
  size_t avail = ws_size > fixed ? ws_size - fixed : 0;
  long rmax = (long)(avail / per_row) & ~255L;
  if (rmax < 256) rmax = 256;
  int R = (int)(rmax < (long)M_TOTAL ? rmax : (long)M_TOTAL);

  float* h    = bufs;                                  // [R][256] f32
  float* kqv  = h   + (size_t)R * 256;                 // [R][768] f32
  float* po   = kqv + (size_t)R * 768;                 // [R][256] f32
  unsigned short* h_bf   = (unsigned short*)(po + (size_t)R * 256);  // [R][256] bf16
  unsigned short* attn_b = h_bf   + (size_t)R * 256;   // [R][256] bf16
  unsigned short* ff1_b  = attn_b + (size_t)R * 256;   // [R][1024] bf16
  float* lf = (float*)(ff1_b + (size_t)R * 1024);      // [R][65] f32

  zero1<<<1, 64, 0, stream>>>(loss_sum);
  convert_qkv<<<CDIV(8 * 768 * 256, 256), 256, 0, stream>>>(Wk, Wq, Wv, WrT);
  convert_t<<<CDIV(8 * 256 * 256, 256), 256, 0, stream>>>(Wp, WpT, 256, 256, 8 * 256 * 256);
  convert_t<<<CDIV(8 * 1024 * 256, 256), 256, 0, stream>>>(W1, W1T, 1024, 256, 8 * 1024 * 256);
  convert_t<<<CDIV(8 * 256 * 1024, 256), 256, 0, stream>>>(W2, W2T, 256, 1024, 8 * 256 * 1024);

  for (int row0 = 0; row0 < M_TOTAL; row0 += R){
    int nr = (M_TOTAL - row0) < R ? (M_TOTAL - row0) : R;
    int eg = CDIV(nr * 256, 256); if (eg > 8192) eg = 8192;
    embed_kernel<<<eg, 256, 0, stream>>>(x, tok, pos, h, h_bf, row0, nr);
    for (int i = 0; i < 8; ++i){
      gemm_bf<false, false><<<dim3(6, nr / 128), 256, 0, stream>>>(
          h_bf, WrT + (size_t)i * 768 * 256, nullptr, kqv, nullptr, 768, 256);
      attn_fused<<<dim3(nr / 32, 4), 128, 0, stream>>>(kqv, attn_b);
      gemm_bf<false, false><<<dim3(2, nr / 128), 256, 0, stream>>>(
          attn_b, WpT + (size_t)i * 256 * 256, bp + i * 256, po, nullptr, 256, 256);
      ln_kernel<<<nr / 4, 256, 0, stream>>>(h, po, ln1g + i * 256, ln1b + i * 256, h_bf);
      gemm_bf<true, true><<<dim3(8, nr / 128), 256, 0, stream>>>(
          h_bf, W1T + (size_t)i * 1024 * 256, b1 + i * 1024, nullptr, ff1_b, 1024, 256);
      gemm_bf<false, false><<<dim3(2, nr / 128), 256, 0, stream>>>(
          ff1_b, W2T + (size_t)i * 256 * 1024, b2 + i * 256, po, nullptr, 256, 1024);
      ln_kernel<<<nr / 4, 256, 0, stream>>>(h, po, ln2g + i * 256, ln2b + i * 256, h_bf);
    }
    logits_kernel<<<CDIV(nr * 65, 256), 256, 0, stream>>>(h, lmW, lmb, lf, out, nr, row0);
    int lb = CDIV(nr, 256);
    loss_kernel<<<lb, 256, 0, stream>>>(lf, y, partial, nr, row0);
    loss_red<<<1, 256, 0, stream>>>(partial, lb, loss_sum);
  }
  loss_fin<<<1, 64, 0, stream>>>(loss_sum, out);
}